// Round 10
// baseline (366.246 us; speedup 1.0000x reference)
//
#include <hip/hip_runtime.h>
#include <math.h>

#define MDIM 1024
#define TSEQ 2048
#define NSOL 5
#define DED  64
#define NBLK 3
#define KITER 2
#define XLDB 1088   // bf16 X leading dim: 1024 sp cols + 64 demb cols
#define NRED 6144   // 5120 P cols + 1024 mp cols
#define RST  64     // dirty-stage grid row stride

typedef __bf16 bf16x8 __attribute__((ext_vector_type(8)));
typedef __bf16 bf16x4 __attribute__((ext_vector_type(4)));
typedef float  f32x4  __attribute__((ext_vector_type(4)));

#define GLDS16(gptr, lptr) __builtin_amdgcn_global_load_lds( \
    (const __attribute__((address_space(1))) unsigned int*)(const void*)(gptr), \
    (__attribute__((address_space(3))) unsigned int*)(void*)(lptr), 16, 0, 0)

__device__ __forceinline__ float gelu_f(float x){
  return 0.5f * x * (1.0f + erff(x * 0.70710678118654752440f));
}
__device__ __forceinline__ float sigmoid_f(float x){ return 1.0f/(1.0f+expf(-x)); }
__device__ __forceinline__ float softplus_f(float x){ return fmaxf(x,0.0f) + log1pf(expf(-fabsf(x))); }

// ---------------- fused convert fp32 -> bf16 transposed; z<12: [1024][1024]; z==12: WpT [1088][1024] ----------------
__global__ __launch_bounds__(256) void k_cvtT13(const float* __restrict__ s0,
    const float* __restrict__ s1, const float* __restrict__ s2, const float* __restrict__ s3,
    const float* __restrict__ s4, __bf16* __restrict__ dst, __bf16* __restrict__ WpT){
  __shared__ float t[32][33];
  const size_t MM = (size_t)MDIM*MDIM;
  int z = blockIdx.z;
  int tx = threadIdx.x & 31, ty = threadIdx.x >> 5;
  if (z < 12){
    if (blockIdx.y >= 32) return;
    const float* s = (z<3)? s0 + (size_t)z*MM : (z<6)? s1 + (size_t)(z-3)*MM :
                     (z<9)? s2 + (size_t)(z-6)*MM : s3 + (size_t)(z-9)*MM;
    __bf16* d = dst + (size_t)z*MM;
    int k0 = blockIdx.y*32, n0 = blockIdx.x*32;
    #pragma unroll
    for (int r=0;r<32;r+=8) t[ty+r][tx] = s[(size_t)(k0+ty+r)*MDIM + n0+tx];
    __syncthreads();
    #pragma unroll
    for (int r=0;r<32;r+=8) d[(size_t)(n0+ty+r)*MDIM + k0+tx] = (__bf16)t[tx][ty+r];
  } else {
    int k0 = blockIdx.y*32, n0 = blockIdx.x*32;   // K=1088 (34 y-blocks), N=1024
    #pragma unroll
    for (int r=0;r<32;r+=8) t[ty+r][tx] = s4[(size_t)(k0+ty+r)*MDIM + n0+tx];
    __syncthreads();
    #pragma unroll
    for (int r=0;r<32;r+=8) WpT[(size_t)(n0+ty+r)*XLDB + k0+tx] = (__bf16)t[tx][ty+r];
  }
}

// ---------------- partial matvecs: P parts (solvent, y=0..4) + mol part (y=5) ----------------
__global__ __launch_bounds__(256) void k_pm(const float* __restrict__ sv,
    const float* __restrict__ spW, const float* __restrict__ mol,
    const float* __restrict__ bhw, float* __restrict__ PART){
  int s = blockIdx.y;
  int j = blockIdx.x*256 + threadIdx.x;
  int z = blockIdx.z, k0 = z*64;
  if (s < NSOL){
    const float* w = spW + (size_t)s*MDIM*MDIM + (size_t)k0*MDIM + j;
    const float* v = sv + s*MDIM + k0;
    float acc = 0.f;
    for (int k=0;k<64;k++) acc = fmaf(v[k], w[(size_t)k*MDIM], acc);
    PART[(size_t)z*NRED + s*MDIM + j] = acc;
  } else {
    const float* w = bhw + (size_t)k0*MDIM + j;
    float acc = 0.f;
    for (int k=0;k<64;k++) acc = fmaf(mol[k0+k], w[(size_t)k*MDIM], acc);
    PART[(size_t)z*NRED + 5120 + j] = acc;
  }
}

// ---------------- reduce partials -> P, mp(+bias); also init speculative state ----------------
__global__ __launch_bounds__(256) void k_red(const float* __restrict__ PART,
    const float* __restrict__ bhb, float* __restrict__ P, float* __restrict__ mp,
    float* __restrict__ prevg, int* __restrict__ dlist, int* __restrict__ dcnt){
  int i = blockIdx.x*256 + threadIdx.x;
  if (i < TSEQ){ prevg[i] = (i==0)? -1.0f : 1.0f; dlist[i] = i; }
  if (i == 0) *dcnt = TSEQ;
  float a = 0.f;
  #pragma unroll
  for (int z=0;z<16;z++) a += PART[(size_t)z*NRED + i];
  if (i < 5120) P[i] = a;
  else mp[i-5120] = a + bhb[i-5120];
}

// ---------------- fused sp0 + demb (bf16 only) ----------------
__global__ __launch_bounds__(256) void k_sp0d(const float* __restrict__ ratios,
    const float* __restrict__ P, const float* __restrict__ bias,
    const float* __restrict__ desc, const float* __restrict__ dw,
    const float* __restrict__ db, __bf16* __restrict__ Xb){
  int t = blockIdx.y;
  if (blockIdx.x < 4){
    int j = blockIdx.x*256 + threadIdx.x;
    const float* r = ratios + t*NSOL;
    float acc = bias[j];
    #pragma unroll
    for (int s=0;s<NSOL;s++) acc = fmaf(r[s], P[s*MDIM+j], acc);
    Xb[(size_t)t*XLDB + j] = (__bf16)gelu_f(acc);
  } else if (threadIdx.x < DED){
    int e = threadIdx.x;
    const float* d = desc + t*6;
    float acc = db[e];
    #pragma unroll
    for (int c=0;c<6;c++) acc = fmaf(d[c], dw[c*DED+e], acc);
    Xb[(size_t)t*XLDB + MDIM + e] = (__bf16)gelu_f(acc);
  }
}

// ---------------- bf16 MFMA GEMM, glds + chunk-swizzle + 3-stage counted-vmcnt pipeline, 512 thr ----------------
// BM=128, BN=64, template BK. 8 waves (4r x 2c), each 32x32 = 2x2 16x16 frags. Residual R bf16.
// Counted vmcnt: each wave drains its OWN stage(t) glds before the barrier -> collectively
// tile t fully landed at barrier exit; stage(t+1) loads stay in flight across the barrier.
template<int BK, bool GELU, bool RES, bool OUTF, bool OUTB, bool Z0>
__global__ __launch_bounds__(512) void k_mfma_gemm(
    const __bf16* __restrict__ A, int lda, int K,
    const __bf16* __restrict__ Bt,           // [N][K] bf16
    const float* __restrict__ bias,          // [N] fp32
    const __bf16* __restrict__ R, int ldr,   // bf16 residual
    float* __restrict__ Cf, int ldcf,
    __bf16* __restrict__ Cb, int ldcb,
    const float* __restrict__ wlast, const float* __restrict__ prevg,
    __bf16* __restrict__ Z0b)
{
  constexpr int CPR = BK/8;        // 16B chunks per row
  constexpr int AG  = BK/32;       // A stage groups per wave
  constexpr int BG  = (BK>=64)? BK/64 : 1;
  constexpr int KS  = BK/32;       // k-subtiles per tile
  constexpr int VPS = AG + BG;     // glds instructions per wave per stage
  __shared__ __attribute__((aligned(16))) __bf16 As[3][128*BK];
  __shared__ __attribute__((aligned(16))) __bf16 Bs[3][64*BK];
  int tid = threadIdx.x;
  int wave = tid>>6, lane = tid&63;
  int row0 = blockIdx.y*128, col0 = blockIdx.x*64;
  int wr = (wave>>1)*32, wc = (wave&1)*32;
  int lr = lane&15;
  f32x4 acc[2][2] = {};
  int NT = K / BK;

  auto stage = [&](int b, int k0){
    #pragma unroll
    for (int p=0;p<AG;p++){
      int q = wave*(AG*64) + p*64 + lane;      // A chunk id
      int r = q/CPR, c = q%CPR, cl = c^(r&7);
      GLDS16(A + (size_t)(row0+r)*lda + k0 + cl*8, &As[b][(wave*(AG*64)+p*64)*8]);
    }
    #pragma unroll
    for (int p=0;p<BG;p++){
      int q = wave*(BG*64) + p*64 + lane;      // B chunk id
      int r = q/CPR, c = q%CPR, cl = c^(r&7);
      GLDS16(Bt + (size_t)(col0+r)*K + k0 + cl*8, &Bs[b][(wave*(BG*64)+p*64)*8]);
    }
  };

  stage(0, 0);
  if (NT > 1) stage(1, BK);
  for (int t=0; t<NT; t++){
    if (t+1 < NT) asm volatile("s_waitcnt vmcnt(%0)" :: "i"(VPS) : "memory");
    else          asm volatile("s_waitcnt vmcnt(0)" ::: "memory");
    __builtin_amdgcn_s_barrier();
    asm volatile("" ::: "memory");
    if (t+2 < NT) stage((t+2)%3, (t+2)*BK);    // prefetch 2 tiles ahead (other buffer)
    int b = t%3;
    #pragma unroll
    for (int ks=0;ks<KS;ks++){
      int c = ks*4 + (lane>>4);                // logical chunk = kk>>3
      bf16x8 af[2], bg[2];
      #pragma unroll
      for (int m=0;m<2;m++){
        int rowA = wr + m*16 + lr;
        af[m] = *(const bf16x8*)&As[b][rowA*BK + ((c ^ (rowA&7))<<3)];
      }
      #pragma unroll
      for (int n=0;n<2;n++){
        int rowB = wc + n*16 + lr;
        bg[n] = *(const bf16x8*)&Bs[b][rowB*BK + ((c ^ (rowB&7))<<3)];
      }
      #pragma unroll
      for (int m=0;m<2;m++)
        #pragma unroll
        for (int n=0;n<2;n++)
          acc[m][n] = __builtin_amdgcn_mfma_f32_16x16x32_bf16(af[m], bg[n], acc[m][n], 0,0,0);
    }
  }
  int rq = (lane>>4)*4;  // verified C/D layout: col = lane&15, row = (lane>>4)*4 + q
  #pragma unroll
  for (int m=0;m<2;m++){
    #pragma unroll
    for (int n=0;n<2;n++){
      int cc = col0 + wc + n*16 + lr;
      float bv = bias[cc];
      #pragma unroll
      for (int q=0;q<4;q++){
        int r = row0 + wr + m*16 + rq + q;
        float v = acc[m][n][q] + bv;
        if (RES)  v += (float)R[(size_t)r*ldr + cc];
        if (GELU) v = gelu_f(v);
        if (OUTF) Cf[(size_t)r*ldcf + cc] = v;
        if (OUTB) Cb[(size_t)r*ldcb + cc] = (__bf16)v;
        if (Z0)   Z0b[(size_t)r*MDIM + cc] = (__bf16)gelu_f(v + prevg[r]*wlast[cc]);
      }
    }
  }
}

// ---------------- batched LayerNorm (float4) -> bf16, optional fused mu/phi ----------------
template<bool MUPHI>
__global__ __launch_bounds__(256) void k_ln(const float* __restrict__ Y, int ldy,
    __bf16* __restrict__ Xb, int ldxb,
    const float* __restrict__ g, const float* __restrict__ b,
    const float* __restrict__ muw, const float* __restrict__ mub,
    const float* __restrict__ phiw, const float* __restrict__ phib,
    float* __restrict__ muA, float* __restrict__ phiA)
{
  int t = blockIdx.x;
  __shared__ float red[16];
  int tid = threadIdx.x;
  f32x4 y = *(const f32x4*)&Y[(size_t)t*ldy + tid*4];
  float s  = y[0]+y[1]+y[2]+y[3];
  float s2 = y[0]*y[0]+y[1]*y[1]+y[2]*y[2]+y[3]*y[3];
  for (int o=32;o>0;o>>=1){ s += __shfl_down(s,o); s2 += __shfl_down(s2,o); }
  int wid = tid>>6, lane = tid&63;
  if (lane==0){ red[wid]=s; red[wid+8]=s2; }
  __syncthreads();
  if (tid==0){
    float a=0.f,c=0.f;
    for (int w=0;w<4;w++){ a+=red[w]; c+=red[w+8]; }
    red[0]=a; red[8]=c;
  }
  __syncthreads();
  float mean = red[0]*(1.0f/MDIM);
  float var  = red[8]*(1.0f/MDIM) - mean*mean;
  float rs = rsqrtf(var + 1e-5f);
  f32x4 gv = *(const f32x4*)&g[tid*4];
  f32x4 bb = *(const f32x4*)&b[tid*4];
  f32x4 v; bf16x4 vb;
  #pragma unroll
  for (int i=0;i<4;i++){ v[i] = gv[i]*(y[i]-mean)*rs + bb[i]; vb[i] = (__bf16)v[i]; }
  *(bf16x4*)&Xb[(size_t)t*ldxb + tid*4] = vb;
  if (MUPHI){
    f32x4 mw = *(const f32x4*)&muw[tid*4];
    f32x4 pw = *(const f32x4*)&phiw[tid*4];
    float sm=0.f, sp=0.f;
    #pragma unroll
    for (int i=0;i<4;i++){ sm = fmaf(v[i], mw[i], sm); sp = fmaf(v[i], pw[i], sp); }
    for (int o=32;o>0;o>>=1){ sm+=__shfl_down(sm,o); sp+=__shfl_down(sp,o); }
    __syncthreads();
    if (lane==0){ red[wid]=sm; red[wid+8]=sp; }
    __syncthreads();
    if (tid==0){
      float a=0.f,c=0.f;
      for (int w=0;w<4;w++){ a+=red[w]; c+=red[w+8]; }
      muA[t]  = sigmoid_f(a + mub[0]);
      phiA[t] = softplus_f(c + phib[0]) + 2.0f;
    }
  }
}

// ================= dirty-row refinement stages (staged, 16-way j-split, 64 thr) =================

// fused z0 + fc1 (head block 0) for dirty rows
__global__ __launch_bounds__(64) void k_fc1z_dirty(
    const float* __restrict__ ZP, const float* __restrict__ wlast,
    const float* __restrict__ prevg,
    const __bf16* __restrict__ Wt, const float* __restrict__ bias,
    const int* __restrict__ dlist, const int* __restrict__ dcnt,
    __bf16* __restrict__ Zb, __bf16* __restrict__ Ob)
{
  __shared__ __bf16 zl[MDIM];
  int nd = *dcnt;
  int jb = blockIdx.x;
  int j = jb*64 + threadIdx.x;
  for (int rs = blockIdx.y; rs < nd; rs += RST){
    int t = dlist[rs];
    float prev = prevg[t];
    #pragma unroll
    for (int q=0;q<16;q++){
      int k = threadIdx.x + 64*q;
      __bf16 v = (__bf16)gelu_f(ZP[(size_t)t*MDIM + k] + prev*wlast[k]);
      zl[k] = v;
      if (jb==0) Zb[(size_t)t*MDIM + k] = v;
    }
    __syncthreads();
    const __bf16* w = Wt + (size_t)j*MDIM;
    float acc = 0.f;
    for (int k=0;k<MDIM;k+=8){
      bf16x8 wv = *(const bf16x8*)&w[k];
      bf16x8 iv = *(const bf16x8*)&zl[k];
      #pragma unroll
      for (int u=0;u<8;u++) acc = fmaf((float)wv[u], (float)iv[u], acc);
    }
    Ob[(size_t)t*MDIM + j] = (__bf16)gelu_f(acc + bias[j]);
    __syncthreads();
  }
}

// fc2 + bf16 residual -> Y fp32, dirty rows
__global__ __launch_bounds__(64) void k_fc2_dirty(
    const __bf16* __restrict__ In, const __bf16* __restrict__ Wt,
    const float* __restrict__ bias, const __bf16* __restrict__ Rz,
    const int* __restrict__ dlist, const int* __restrict__ dcnt,
    float* __restrict__ Of)
{
  int nd = *dcnt;
  int j = blockIdx.x*64 + threadIdx.x;
  for (int rs = blockIdx.y; rs < nd; rs += RST){
    int t = dlist[rs];
    const __bf16* in = In + (size_t)t*MDIM;
    const __bf16* w  = Wt + (size_t)j*MDIM;
    float acc = 0.f;
    for (int k=0;k<MDIM;k+=8){
      bf16x8 wv = *(const bf16x8*)&w[k];
      bf16x8 iv = *(const bf16x8*)&in[k];
      #pragma unroll
      for (int u=0;u<8;u++) acc = fmaf((float)wv[u], (float)iv[u], acc);
    }
    Of[(size_t)t*MDIM + j] = acc + bias[j] + (float)Rz[(size_t)t*MDIM + j];
  }
}

// fused LN (of Y) + fc1 matvec for dirty rows: single-wave LN -> LDS, then 64-output matvec
__global__ __launch_bounds__(64) void k_lnfc1_dirty(
    const float* __restrict__ Y,
    const float* __restrict__ g, const float* __restrict__ b,
    const __bf16* __restrict__ Wt, const float* __restrict__ fbias,
    const int* __restrict__ dlist, const int* __restrict__ dcnt,
    __bf16* __restrict__ Zb, __bf16* __restrict__ Ob)
{
  __shared__ __bf16 zl[MDIM];
  int nd = *dcnt;
  int jb = blockIdx.x;
  int j = jb*64 + threadIdx.x;
  for (int rs = blockIdx.y; rs < nd; rs += RST){
    int t = dlist[rs];
    float y[16]; float s=0.f, s2=0.f;
    #pragma unroll
    for (int q=0;q<16;q++){
      y[q] = Y[(size_t)t*MDIM + threadIdx.x + 64*q];
      s += y[q]; s2 += y[q]*y[q];
    }
    for (int o=32;o>0;o>>=1){ s += __shfl_down(s,o); s2 += __shfl_down(s2,o); }
    float tot  = __shfl(s, 0);
    float tot2 = __shfl(s2, 0);
    float mean = tot*(1.0f/MDIM);
    float var  = tot2*(1.0f/MDIM) - mean*mean;
    float rs2 = rsqrtf(var + 1e-5f);
    #pragma unroll
    for (int q=0;q<16;q++){
      int k = threadIdx.x + 64*q;
      __bf16 v = (__bf16)(g[k]*(y[q]-mean)*rs2 + b[k]);
      zl[k] = v;
      if (jb==0) Zb[(size_t)t*MDIM + k] = v;
    }
    __syncthreads();
    const __bf16* w = Wt + (size_t)j*MDIM;
    float acc = 0.f;
    for (int k=0;k<MDIM;k+=8){
      bf16x8 wv = *(const bf16x8*)&w[k];
      bf16x8 iv = *(const bf16x8*)&zl[k];
      #pragma unroll
      for (int u=0;u<8;u++) acc = fmaf((float)wv[u], (float)iv[u], acc);
    }
    Ob[(size_t)t*MDIM + j] = (__bf16)gelu_f(acc + fbias[j]);
    __syncthreads();
  }
}

// final LN + mu/phi for dirty rows (single wave per row-slot, 64 thr)
__global__ __launch_bounds__(64) void k_lnmp_dirty(
    const float* __restrict__ Y,
    const float* __restrict__ g, const float* __restrict__ b,
    const int* __restrict__ dlist, const int* __restrict__ dcnt,
    const float* __restrict__ muw, const float* __restrict__ mub,
    const float* __restrict__ phiw, const float* __restrict__ phib,
    float* __restrict__ muA, float* __restrict__ phiA)
{
  int nd = *dcnt;
  for (int rs = blockIdx.x; rs < nd; rs += RST){
    int t = dlist[rs];
    float y[16]; float s=0.f, s2=0.f;
    #pragma unroll
    for (int q=0;q<16;q++){
      y[q] = Y[(size_t)t*MDIM + threadIdx.x + 64*q];
      s += y[q]; s2 += y[q]*y[q];
    }
    for (int o=32;o>0;o>>=1){ s += __shfl_down(s,o); s2 += __shfl_down(s2,o); }
    float tot  = __shfl(s, 0);
    float tot2 = __shfl(s2, 0);
    float mean = tot*(1.0f/MDIM);
    float var  = tot2*(1.0f/MDIM) - mean*mean;
    float rs2 = rsqrtf(var + 1e-5f);
    float sm=0.f, sp=0.f;
    #pragma unroll
    for (int q=0;q<16;q++){
      int k = threadIdx.x + 64*q;
      float v = g[k]*(y[q]-mean)*rs2 + b[k];
      sm = fmaf(v, muw[k], sm); sp = fmaf(v, phiw[k], sp);
    }
    for (int o=32;o>0;o>>=1){ sm+=__shfl_down(sm,o); sp+=__shfl_down(sp,o); }
    if (threadIdx.x==0){
      muA[t]  = sigmoid_f(sm + mub[0]);
      phiA[t] = softplus_f(sp + phib[0]) + 2.0f;
    }
  }
}

// ---------------- segmented prefix-product scan (wave shfl, 2 barriers) + dirty detect + output ----------------
__global__ __launch_bounds__(1024) void k_scan(
    const float* __restrict__ muA, const float* __restrict__ phiA,
    const unsigned char* __restrict__ bmask,
    float* __restrict__ prevg, int* __restrict__ dlist, int* __restrict__ dcnt,
    float* __restrict__ out)
{
  if (*dcnt == 0) return;
  __shared__ float aggP[16];
  __shared__ unsigned aggF[16];
  __shared__ float wprP[16];
  __shared__ unsigned wprF[16];
  __shared__ int cnt;
  int tid = threadIdx.x;
  int wid = tid>>6, lane = tid&63;
  if (tid==0) cnt = 0;
  int i0 = wid*128 + lane*2;            // this lane's two elements
  float mu0 = muA[i0], mu1 = muA[i0+1];
  float p0 = 1.0f - mu0, p1 = 1.0f - mu1;
  unsigned f0 = (i0==0) || (bmask[i0] != 0);
  unsigned f1 = (bmask[i0+1] != 0);
  float    sp_ = f1 ? p1 : p0*p1;
  unsigned sf_ = f0|f1;
  #pragma unroll
  for (int off=1; off<64; off<<=1){
    float    op = __shfl_up(sp_, off);
    unsigned of = __shfl_up(sf_, off);
    if (lane >= off && !sf_){ sp_ = op*sp_; sf_ = of; }
  }
  if (lane==63){ aggP[wid]=sp_; aggF[wid]=sf_; }
  __syncthreads();
  if (wid==0 && lane<16){
    float ap = aggP[lane]; unsigned af = aggF[lane];
    #pragma unroll
    for (int off=1; off<16; off<<=1){
      float    op = __shfl_up(ap, off);
      unsigned of = __shfl_up(af, off);
      if (lane >= off && !af){ ap = op*ap; af = of; }
    }
    wprP[lane]=ap; wprF[lane]=af;
  }
  __syncthreads();
  float    wpP = (wid==0)? 1.0f : wprP[wid-1];
  float    lpP = __shfl_up(sp_, 1);
  unsigned lpF = __shfl_up(sf_, 1);
  float exP;
  if (lane==0){ exP = wpP; }
  else        { exP = lpF ? lpP : wpP*lpP; }
  float i0P = f0 ? p0 : exP*p0;
  float i1P = f1 ? p1 : i0P*p1;
  float prev0 = (i0==0)? -1.0f : (1.0f - exP);
  float prev1 = 1.0f - i0P;
  float rf0 = 1.0f - i0P, rf1 = 1.0f - i1P;
  out[i0]   = rf0;  out[i0+1]   = rf1;
  out[TSEQ+i0] = mu0; out[TSEQ+i0+1] = mu1;
  out[2*TSEQ+i0] = phiA[i0]; out[2*TSEQ+i0+1] = phiA[i0+1];
  float old0 = prevg[i0], old1 = prevg[i0+1];
  prevg[i0] = prev0; prevg[i0+1] = prev1;
  if (fabsf(prev0 - old0) > 1e-3f){ int pos = atomicAdd(&cnt,1); dlist[pos] = i0; }
  if (fabsf(prev1 - old1) > 1e-3f){ int pos = atomicAdd(&cnt,1); dlist[pos] = i0+1; }
  __syncthreads();
  if (tid==0) *dcnt = cnt;
}

extern "C" void kernel_launch(void* const* d_in, const int* in_sizes, int n_in,
                              void* d_out, int out_size, void* d_ws, size_t ws_size,
                              hipStream_t stream) {
  const float* mol       = (const float*)d_in[0];
  const float* ratios    = (const float*)d_in[1];
  const float* desc      = (const float*)d_in[2];
  const float* svvec     = (const float*)d_in[3];
  const unsigned char* bmask = (const unsigned char*)d_in[4];
  const float* sp_proj_w = (const float*)d_in[5];
  const float* sp_proj_b = (const float*)d_in[6];
  const float* sp_fc1_w  = (const float*)d_in[7];
  const float* sp_fc1_b  = (const float*)d_in[8];
  const float* sp_fc2_w  = (const float*)d_in[9];
  const float* sp_fc2_b  = (const float*)d_in[10];
  const float* sp_ln_g   = (const float*)d_in[11];
  const float* sp_ln_b   = (const float*)d_in[12];
  const float* desc_w    = (const float*)d_in[13];
  const float* desc_b    = (const float*)d_in[14];
  const float* bh_proj_w = (const float*)d_in[15];
  const float* bh_proj_b = (const float*)d_in[16];
  const float* bh_fc1_w  = (const float*)d_in[17];
  const float* bh_fc1_b  = (const float*)d_in[18];
  const float* bh_fc2_w  = (const float*)d_in[19];
  const float* bh_fc2_b  = (const float*)d_in[20];
  const float* bh_ln_g   = (const float*)d_in[21];
  const float* bh_ln_b   = (const float*)d_in[22];
  const float* mu_w      = (const float*)d_in[23];
  const float* mu_b      = (const float*)d_in[24];
  const float* phi_w     = (const float*)d_in[25];
  const float* phi_b     = (const float*)d_in[26];
  float* out = (float*)d_out;

  char* p = (char*)d_ws;
  auto alloc = [&](size_t bytes)->char*{ char* r = p; p += (bytes + 255) & ~(size_t)255; return r; };
  const size_t MM = (size_t)MDIM*MDIM;
  __bf16* Xb   = (__bf16*)alloc((size_t)TSEQ*XLDB*2);    // bf16 [sp|demb]
  __bf16* Zb   = (__bf16*)alloc((size_t)TSEQ*MDIM*2);    // head bf16 z
  float*  Y    = (float*)alloc((size_t)TSEQ*MDIM*4);     // fp32 pre-LN
  float*  ZP   = (float*)alloc((size_t)TSEQ*MDIM*4);     // persistent head pre-activation
  __bf16* Hb16 = (__bf16*)alloc((size_t)TSEQ*MDIM*2);
  __bf16* WALL = (__bf16*)alloc(12*MM*2);                // W1T|W2T|U1T|U2T (3 blocks each)
  __bf16* WpT  = (__bf16*)alloc((size_t)MDIM*XLDB*2);    // [1024][1088]
  float*  PART = (float*)alloc((size_t)16*NRED*4);
  float*  P    = (float*)alloc((size_t)NSOL*MDIM*4);
  float*  mp   = (float*)alloc(MDIM*4);
  float*  prevg= (float*)alloc(TSEQ*4);
  float*  muA  = (float*)alloc(TSEQ*4);
  float*  phiA = (float*)alloc(TSEQ*4);
  int*    dlist= (int*)alloc(TSEQ*4);
  int*    dcnt = (int*)alloc(256);
  __bf16* W1T = WALL, *W2T = WALL + 3*MM, *U1T = WALL + 6*MM, *U2T = WALL + 9*MM;

  k_cvtT13<<<dim3(32,34,13),256,0,stream>>>(sp_fc1_w, sp_fc2_w, bh_fc1_w, bh_fc2_w,
      bh_proj_w + MM, WALL, WpT);
  k_pm<<<dim3(4,6,16),256,0,stream>>>(svvec, sp_proj_w, mol, bh_proj_w, PART);
  k_red<<<dim3(NRED/256),256,0,stream>>>(PART, bh_proj_b, P, mp, prevg, dlist, dcnt);
  k_sp0d<<<dim3(5,TSEQ),256,0,stream>>>(ratios, P, sp_proj_b, desc, desc_w, desc_b, Xb);

  const float* wlast = bh_proj_w + (size_t)2112*MDIM;
  // sp residual chain (bf16 MFMA GEMMs, BK=128, counted-vmcnt pipeline)
  for (int i=0;i<NBLK;i++){
    k_mfma_gemm<128,true,false,false,true,false><<<dim3(16,16),512,0,stream>>>(
        Xb, XLDB, MDIM, W1T + i*MM, sp_fc1_b + i*MDIM, nullptr, 0,
        nullptr, 0, Hb16, MDIM, nullptr, nullptr, nullptr);
    k_mfma_gemm<128,false,true,true,false,false><<<dim3(16,16),512,0,stream>>>(
        Hb16, MDIM, MDIM, W2T + i*MM, sp_fc2_b + i*MDIM, Xb, XLDB,
        Y, MDIM, nullptr, 0, nullptr, nullptr, nullptr);
    k_ln<false><<<dim3(TSEQ),256,0,stream>>>(Y, MDIM, Xb, XLDB,
        sp_ln_g + i*MDIM, sp_ln_b + i*MDIM,
        nullptr, nullptr, nullptr, nullptr, nullptr, nullptr);
  }
  // z_pre GEMM (K=1088, BK=64) with fused z0 epilogue: ZP + speculative gelu -> Zb
  k_mfma_gemm<64,false,false,true,false,true><<<dim3(16,16),512,0,stream>>>(
      Xb, XLDB, XLDB, WpT, mp, nullptr, 0, ZP, MDIM, nullptr, 0,
      wlast, prevg, Zb);

  // ---- iteration 1: batched head with speculative prev ----
  for (int i=0;i<NBLK;i++){
    k_mfma_gemm<128,true,false,false,true,false><<<dim3(16,16),512,0,stream>>>(
        Zb, MDIM, MDIM, U1T + i*MM, bh_fc1_b + i*MDIM, nullptr, 0,
        nullptr, 0, Hb16, MDIM, nullptr, nullptr, nullptr);
    k_mfma_gemm<128,false,true,true,false,false><<<dim3(16,16),512,0,stream>>>(
        Hb16, MDIM, MDIM, U2T + i*MM, bh_fc2_b + i*MDIM, Zb, MDIM,
        Y, MDIM, nullptr, 0, nullptr, nullptr, nullptr);
    if (i < NBLK-1)
      k_ln<false><<<dim3(TSEQ),256,0,stream>>>(Y, MDIM, Zb, MDIM,
          bh_ln_g + i*MDIM, bh_ln_b + i*MDIM,
          nullptr, nullptr, nullptr, nullptr, nullptr, nullptr);
    else
      k_ln<true><<<dim3(TSEQ),256,0,stream>>>(Y, MDIM, Zb, MDIM,
          bh_ln_g + i*MDIM, bh_ln_b + i*MDIM,
          mu_w, mu_b, phi_w, phi_b, muA, phiA);
  }
  k_scan<<<dim3(1),1024,0,stream>>>(muA, phiA, bmask, prevg, dlist, dcnt, out);

  // ---- refinement: one staged dirty-row pass + final scan ----
  for (int it=1; it<KITER; it++){
    k_fc1z_dirty<<<dim3(16,RST),64,0,stream>>>(ZP, wlast, prevg,
        U1T, bh_fc1_b, dlist, dcnt, Zb, Hb16);
    k_fc2_dirty<<<dim3(16,RST),64,0,stream>>>(
        Hb16, U2T, bh_fc2_b, Zb, dlist, dcnt, Y);
    for (int i=1;i<NBLK;i++){
      k_lnfc1_dirty<<<dim3(16,RST),64,0,stream>>>(Y,
          bh_ln_g + (i-1)*MDIM, bh_ln_b + (i-1)*MDIM,
          U1T + i*MM, bh_fc1_b + i*MDIM, dlist, dcnt, Zb, Hb16);
      k_fc2_dirty<<<dim3(16,RST),64,0,stream>>>(
          Hb16, U2T + i*MM, bh_fc2_b + i*MDIM, Zb, dlist, dcnt, Y);
    }
    k_lnmp_dirty<<<dim3(RST),64,0,stream>>>(Y,
        bh_ln_g + (NBLK-1)*MDIM, bh_ln_b + (NBLK-1)*MDIM,
        dlist, dcnt, mu_w, mu_b, phi_w, phi_b, muA, phiA);
    k_scan<<<dim3(1),1024,0,stream>>>(muA, phiA, bmask, prevg, dlist, dcnt, out);
  }
  (void)in_sizes; (void)n_in; (void)out_size; (void)ws_size;
}

// Round 11
// 354.940 us; speedup vs baseline: 1.0319x; 1.0319x over previous
//
#include <hip/hip_runtime.h>
#include <math.h>

#define MDIM 1024
#define TSEQ 2048
#define NSOL 5
#define DED  64
#define NBLK 3
#define KITER 2
#define XLDB 1088   // bf16 X leading dim: 1024 sp cols + 64 demb cols
#define NRED 14336  // 5120 P + 1024 mp + 4*2048 S-sums
#define RST  64     // dirty-stage grid row stride

typedef __bf16 bf16x8 __attribute__((ext_vector_type(8)));
typedef __bf16 bf16x4 __attribute__((ext_vector_type(4)));
typedef float  f32x4  __attribute__((ext_vector_type(4)));

#define GLDS16(gptr, lptr) __builtin_amdgcn_global_load_lds( \
    (const __attribute__((address_space(1))) unsigned int*)(const void*)(gptr), \
    (__attribute__((address_space(3))) unsigned int*)(void*)(lptr), 16, 0, 0)

__device__ __forceinline__ float gelu_f(float x){
  return 0.5f * x * (1.0f + erff(x * 0.70710678118654752440f));
}
__device__ __forceinline__ float sigmoid_f(float x){ return 1.0f/(1.0f+expf(-x)); }
__device__ __forceinline__ float softplus_f(float x){ return fmaxf(x,0.0f) + log1pf(expf(-fabsf(x))); }

// ---- convert fp32 -> bf16 transposed; z<12: [1024][1024] (fold g for z in {1,2,7,8}); z==12: WpT ----
__global__ __launch_bounds__(256) void k_cvtT13(const float* __restrict__ s0,
    const float* __restrict__ s1, const float* __restrict__ s2, const float* __restrict__ s3,
    const float* __restrict__ s4, __bf16* __restrict__ dst, __bf16* __restrict__ WpT,
    const float* __restrict__ spg, const float* __restrict__ bhg){
  __shared__ float t[32][33];
  const size_t MM = (size_t)MDIM*MDIM;
  int z = blockIdx.z;
  int tx = threadIdx.x & 31, ty = threadIdx.x >> 5;
  if (z < 12){
    if (blockIdx.y >= 32) return;
    const float* s = (z<3)? s0 + (size_t)z*MM : (z<6)? s1 + (size_t)(z-3)*MM :
                     (z<9)? s2 + (size_t)(z-6)*MM : s3 + (size_t)(z-9)*MM;
    const float* gf = (z==1)? spg : (z==2)? spg+MDIM : (z==7)? bhg : (z==8)? bhg+MDIM : nullptr;
    __bf16* d = dst + (size_t)z*MM;
    int k0 = blockIdx.y*32, n0 = blockIdx.x*32;
    #pragma unroll
    for (int r=0;r<32;r+=8){
      float val = s[(size_t)(k0+ty+r)*MDIM + n0+tx];
      if (gf) val *= gf[k0+ty+r];
      t[ty+r][tx] = val;
    }
    __syncthreads();
    #pragma unroll
    for (int r=0;r<32;r+=8) d[(size_t)(n0+ty+r)*MDIM + k0+tx] = (__bf16)t[tx][ty+r];
  } else {
    int k0 = blockIdx.y*32, n0 = blockIdx.x*32;   // K=1088 (34 y-blocks), N=1024
    #pragma unroll
    for (int r=0;r<32;r+=8) t[ty+r][tx] = s4[(size_t)(k0+ty+r)*MDIM + n0+tx];
    __syncthreads();
    #pragma unroll
    for (int r=0;r<32;r+=8) WpT[(size_t)(n0+ty+r)*XLDB + k0+tx] = (__bf16)t[tx][ty+r];
  }
}

// ---- partial matvecs: P (y=0..4), mol (y=5), S1/Sb column-sums of folded fc1 weights (y=6..9) ----
__global__ __launch_bounds__(256) void k_pm(const float* __restrict__ sv,
    const float* __restrict__ spW, const float* __restrict__ mol,
    const float* __restrict__ bhw, float* __restrict__ PART,
    const float* __restrict__ spfc1w, const float* __restrict__ bhfc1w,
    const float* __restrict__ splg, const float* __restrict__ splb,
    const float* __restrict__ bhlg, const float* __restrict__ bhlb){
  const size_t MM = (size_t)MDIM*MDIM;
  int s = blockIdx.y;
  int j = blockIdx.x*256 + threadIdx.x;
  int z = blockIdx.z, k0 = z*64;
  if (s < NSOL){
    const float* w = spW + (size_t)s*MM + (size_t)k0*MDIM + j;
    const float* v = sv + s*MDIM + k0;
    float acc = 0.f;
    for (int k=0;k<64;k++) acc = fmaf(v[k], w[(size_t)k*MDIM], acc);
    PART[(size_t)z*NRED + s*MDIM + j] = acc;
  } else if (s == NSOL){
    const float* w = bhw + (size_t)k0*MDIM + j;
    float acc = 0.f;
    for (int k=0;k<64;k++) acc = fmaf(mol[k0+k], w[(size_t)k*MDIM], acc);
    PART[(size_t)z*NRED + 5120 + j] = acc;
  } else {
    int m = s - 6;  // 0,1: sp blocks 1,2 ; 2,3: bh blocks 1,2
    const float* W = (m<2)? spfc1w + (size_t)(m+1)*MM : bhfc1w + (size_t)(m-1)*MM;
    const float* g = (m<2)? splg + m*MDIM : bhlg + (m-2)*MDIM;
    const float* b = (m<2)? splb + m*MDIM : bhlb + (m-2)*MDIM;
    float aS=0.f, aB=0.f;
    for (int k=0;k<64;k++){
      float w = W[(size_t)(k0+k)*MDIM + j];
      aS = fmaf(g[k0+k], w, aS);
      aB = fmaf(b[k0+k], w, aB);
    }
    PART[(size_t)z*NRED + 6144 + m*2048 + j] = aS;
    PART[(size_t)z*NRED + 6144 + m*2048 + 1024 + j] = aB;
  }
}

// ---- reduce partials -> P, mp, S1buf, biasF; init speculative state ----
__global__ __launch_bounds__(256) void k_red(const float* __restrict__ PART,
    const float* __restrict__ bhb, float* __restrict__ P, float* __restrict__ mp,
    float* __restrict__ prevg, int* __restrict__ dlist, int* __restrict__ dcnt,
    const float* __restrict__ spfc1b, const float* __restrict__ bhfc1b,
    float* __restrict__ S1buf, float* __restrict__ biasF){
  int i = blockIdx.x*256 + threadIdx.x;
  if (i < TSEQ){ prevg[i] = (i==0)? -1.0f : 1.0f; dlist[i] = i; }
  if (i == 0) *dcnt = TSEQ;
  float a = 0.f;
  #pragma unroll
  for (int z=0;z<16;z++) a += PART[(size_t)z*NRED + i];
  if (i < 5120) P[i] = a;
  else if (i < 6144) mp[i-5120] = a + bhb[i-5120];
  else {
    int off = i - 6144, m = off>>11, r = off&2047;
    if (r < 1024) S1buf[(m<<10)+r] = a;
    else {
      const float* b1 = ((m<2)? spfc1b : bhfc1b) + (((m&1)+1)<<10);
      biasF[(m<<10)+(r-1024)] = a + b1[r-1024];
    }
  }
}

// ---- fused sp0 + demb (bf16 only) ----
__global__ __launch_bounds__(256) void k_sp0d(const float* __restrict__ ratios,
    const float* __restrict__ P, const float* __restrict__ bias,
    const float* __restrict__ desc, const float* __restrict__ dw,
    const float* __restrict__ db, __bf16* __restrict__ Xb){
  int t = blockIdx.y;
  if (blockIdx.x < 4){
    int j = blockIdx.x*256 + threadIdx.x;
    const float* r = ratios + t*NSOL;
    float acc = bias[j];
    #pragma unroll
    for (int s=0;s<NSOL;s++) acc = fmaf(r[s], P[s*MDIM+j], acc);
    Xb[(size_t)t*XLDB + j] = (__bf16)gelu_f(acc);
  } else if (threadIdx.x < DED){
    int e = threadIdx.x;
    const float* d = desc + t*6;
    float acc = db[e];
    #pragma unroll
    for (int c=0;c<6;c++) acc = fmaf(d[c], dw[c*DED+e], acc);
    Xb[(size_t)t*XLDB + MDIM + e] = (__bf16)gelu_f(acc);
  }
}

// ---- bf16 MFMA GEMM: glds+chunk-swizzle, 3-stage counted-vmcnt, XCD swizzle, LN-fold variants ----
template<int BK, bool GELU, bool RES, bool RESLN, bool OUTF, bool OUTB, bool Z0, bool LNFOLD, bool STATS>
__global__ __launch_bounds__(512) void k_mfma_gemm(
    const __bf16* __restrict__ A, int lda, int K,
    const __bf16* __restrict__ Bt,
    const float* __restrict__ bias,
    const __bf16* __restrict__ R, int ldr,
    float* __restrict__ Cf, int ldcf,
    __bf16* __restrict__ Cb, int ldcb,
    const float* __restrict__ wlast, const float* __restrict__ prevg,
    __bf16* __restrict__ Z0b,
    const float* __restrict__ pSin, const float* __restrict__ pQin,
    float* __restrict__ pSout, float* __restrict__ pQout,
    const float* __restrict__ S1, const float* __restrict__ biasF,
    const float* __restrict__ lng, const float* __restrict__ lnb)
{
  constexpr int CPR = BK/8;
  constexpr int AG  = BK/32;
  constexpr int BG  = (BK>=64)? BK/64 : 1;
  constexpr int KS  = BK/32;
  constexpr int VPS = AG + BG;
  __shared__ __attribute__((aligned(16))) __bf16 As[3][128*BK];
  __shared__ __attribute__((aligned(16))) __bf16 Bs[3][64*BK];
  __shared__ float srowS[128], srowQ[128];
  __shared__ float sr2S[2][128], sr2Q[2][128];
  int tid = threadIdx.x;
  int wave = tid>>6, lane = tid&63;
  // XCD-aware swizzle: linear id n -> XCD n&7; give each XCD 2 row-panels
  int nlin = blockIdx.y*16 + blockIdx.x;
  int kq = nlin>>3;
  int by = 2*(nlin&7) + (kq>>4), bx = kq&15;
  int row0 = by*128, col0 = bx*64;
  int wr = (wave>>1)*32, wc = (wave&1)*32;
  int lr = lane&15;
  f32x4 acc[2][2] = {};
  int NT = K / BK;

  auto stage = [&](int b, int k0){
    #pragma unroll
    for (int p=0;p<AG;p++){
      int q = wave*(AG*64) + p*64 + lane;
      int r = q/CPR, c = q%CPR, cl = c^(r&7);
      GLDS16(A + (size_t)(row0+r)*lda + k0 + cl*8, &As[b][(wave*(AG*64)+p*64)*8]);
    }
    #pragma unroll
    for (int p=0;p<BG;p++){
      int q = wave*(BG*64) + p*64 + lane;
      int r = q/CPR, c = q%CPR, cl = c^(r&7);
      GLDS16(Bt + (size_t)(col0+r)*K + k0 + cl*8, &Bs[b][(wave*(BG*64)+p*64)*8]);
    }
  };

  stage(0, 0);
  if (NT > 1) stage(1, BK);
  if (LNFOLD || RESLN){
    if (tid < 128){
      float a=0.f, b2=0.f;
      #pragma unroll
      for (int x2=0;x2<16;x2++){
        a  += pSin[x2*2048 + row0 + tid];
        b2 += pQin[x2*2048 + row0 + tid];
      }
      srowS[tid]=a; srowQ[tid]=b2;
    }
    __syncthreads();
  }
  for (int t=0; t<NT; t++){
    if (t+1 < NT) asm volatile("s_waitcnt vmcnt(%0)" :: "i"(VPS) : "memory");
    else          asm volatile("s_waitcnt vmcnt(0)" ::: "memory");
    __builtin_amdgcn_s_barrier();
    asm volatile("" ::: "memory");
    if (t+2 < NT) stage((t+2)%3, (t+2)*BK);
    int b = t%3;
    #pragma unroll
    for (int ks=0;ks<KS;ks++){
      int c = ks*4 + (lane>>4);
      bf16x8 af[2], bg[2];
      #pragma unroll
      for (int m=0;m<2;m++){
        int rowA = wr + m*16 + lr;
        af[m] = *(const bf16x8*)&As[b][rowA*BK + ((c ^ (rowA&7))<<3)];
      }
      #pragma unroll
      for (int n=0;n<2;n++){
        int rowB = wc + n*16 + lr;
        bg[n] = *(const bf16x8*)&Bs[b][rowB*BK + ((c ^ (rowB&7))<<3)];
      }
      #pragma unroll
      for (int m=0;m<2;m++)
        #pragma unroll
        for (int n=0;n<2;n++)
          acc[m][n] = __builtin_amdgcn_mfma_f32_16x16x32_bf16(af[m], bg[n], acc[m][n], 0,0,0);
    }
  }
  int rq = (lane>>4)*4;  // C/D layout: col = lane&15, row = (lane>>4)*4 + q
  float sst[2][4], ssq[2][4];
  if (STATS){
    #pragma unroll
    for (int m=0;m<2;m++)
      #pragma unroll
      for (int q=0;q<4;q++){ sst[m][q]=0.f; ssq[m][q]=0.f; }
  }
  #pragma unroll
  for (int m=0;m<2;m++){
    #pragma unroll
    for (int n=0;n<2;n++){
      int cc = col0 + wc + n*16 + lr;
      float bv  = LNFOLD ? 0.f : bias[cc];
      float s1v = LNFOLD ? S1[cc] : 0.f;
      float bfv = LNFOLD ? biasF[cc] : 0.f;
      float gcc = RESLN ? lng[cc] : 0.f;
      float bcc = RESLN ? lnb[cc] : 0.f;
      #pragma unroll
      for (int q=0;q<4;q++){
        int r = row0 + wr + m*16 + rq + q;
        int rl = r - row0;
        float v = acc[m][n][q];
        if (LNFOLD){
          float s = srowS[rl], q2 = srowQ[rl];
          float mean = s*(1.0f/MDIM);
          float var  = q2*(1.0f/MDIM) - mean*mean;
          float rs   = rsqrtf(var + 1e-5f);
          v = rs*v - rs*mean*s1v + bfv;
          v = gelu_f(v);
        } else {
          v += bv;
          if (RES) v += (float)R[(size_t)r*ldr + cc];
          if (RESLN){
            float s = srowS[rl], q2 = srowQ[rl];
            float mean = s*(1.0f/MDIM);
            float var  = q2*(1.0f/MDIM) - mean*mean;
            float rs   = rsqrtf(var + 1e-5f);
            v += gcc*((float)R[(size_t)r*ldr + cc] - mean)*rs + bcc;
          }
          if (GELU) v = gelu_f(v);
        }
        if (STATS){ sst[m][q] += v; ssq[m][q] += v*v; }
        if (OUTF) Cf[(size_t)r*ldcf + cc] = v;
        if (OUTB) Cb[(size_t)r*ldcb + cc] = (__bf16)v;
        if (Z0)   Z0b[(size_t)r*MDIM + cc] = (__bf16)gelu_f(v + prevg[r]*wlast[cc]);
      }
    }
  }
  if (STATS){
    #pragma unroll
    for (int off=1; off<16; off<<=1){
      #pragma unroll
      for (int m=0;m<2;m++)
        #pragma unroll
        for (int q=0;q<4;q++){
          sst[m][q] += __shfl_xor(sst[m][q], off);
          ssq[m][q] += __shfl_xor(ssq[m][q], off);
        }
    }
    if ((lane&15)==0){
      #pragma unroll
      for (int m=0;m<2;m++)
        #pragma unroll
        for (int q=0;q<4;q++){
          int rl = wr + m*16 + rq + q;
          sr2S[wave&1][rl] = sst[m][q];
          sr2Q[wave&1][rl] = ssq[m][q];
        }
    }
    __syncthreads();
    if (tid < 128){
      pSout[bx*2048 + row0 + tid] = sr2S[0][tid] + sr2S[1][tid];
      pQout[bx*2048 + row0 + tid] = sr2Q[0][tid] + sr2Q[1][tid];
    }
  }
}

// ---- batched LayerNorm (float4) -> bf16, optional fused mu/phi (used only for block-3 LNs) ----
template<bool MUPHI>
__global__ __launch_bounds__(256) void k_ln(const float* __restrict__ Y, int ldy,
    __bf16* __restrict__ Xb, int ldxb,
    const float* __restrict__ g, const float* __restrict__ b,
    const float* __restrict__ muw, const float* __restrict__ mub,
    const float* __restrict__ phiw, const float* __restrict__ phib,
    float* __restrict__ muA, float* __restrict__ phiA)
{
  int t = blockIdx.x;
  __shared__ float red[16];
  int tid = threadIdx.x;
  f32x4 y = *(const f32x4*)&Y[(size_t)t*ldy + tid*4];
  float s  = y[0]+y[1]+y[2]+y[3];
  float s2 = y[0]*y[0]+y[1]*y[1]+y[2]*y[2]+y[3]*y[3];
  for (int o=32;o>0;o>>=1){ s += __shfl_down(s,o); s2 += __shfl_down(s2,o); }
  int wid = tid>>6, lane = tid&63;
  if (lane==0){ red[wid]=s; red[wid+8]=s2; }
  __syncthreads();
  if (tid==0){
    float a=0.f,c=0.f;
    for (int w=0;w<4;w++){ a+=red[w]; c+=red[w+8]; }
    red[0]=a; red[8]=c;
  }
  __syncthreads();
  float mean = red[0]*(1.0f/MDIM);
  float var  = red[8]*(1.0f/MDIM) - mean*mean;
  float rs = rsqrtf(var + 1e-5f);
  f32x4 gv = *(const f32x4*)&g[tid*4];
  f32x4 bb = *(const f32x4*)&b[tid*4];
  f32x4 v; bf16x4 vb;
  #pragma unroll
  for (int i=0;i<4;i++){ v[i] = gv[i]*(y[i]-mean)*rs + bb[i]; vb[i] = (__bf16)v[i]; }
  *(bf16x4*)&Xb[(size_t)t*ldxb + tid*4] = vb;
  if (MUPHI){
    f32x4 mw = *(const f32x4*)&muw[tid*4];
    f32x4 pw = *(const f32x4*)&phiw[tid*4];
    float sm=0.f, sp=0.f;
    #pragma unroll
    for (int i=0;i<4;i++){ sm = fmaf(v[i], mw[i], sm); sp = fmaf(v[i], pw[i], sp); }
    for (int o=32;o>0;o>>=1){ sm+=__shfl_down(sm,o); sp+=__shfl_down(sp,o); }
    __syncthreads();
    if (lane==0){ red[wid]=sm; red[wid+8]=sp; }
    __syncthreads();
    if (tid==0){
      float a=0.f,c=0.f;
      for (int w=0;w<4;w++){ a+=red[w]; c+=red[w+8]; }
      muA[t]  = sigmoid_f(a + mub[0]);
      phiA[t] = softplus_f(c + phib[0]) + 2.0f;
    }
  }
}

// ================= dirty-row refinement stages =================

__global__ __launch_bounds__(64) void k_fc1z_dirty(
    const float* __restrict__ ZP, const float* __restrict__ wlast,
    const float* __restrict__ prevg,
    const __bf16* __restrict__ Wt, const float* __restrict__ bias,
    const int* __restrict__ dlist, const int* __restrict__ dcnt,
    __bf16* __restrict__ Zb, __bf16* __restrict__ Ob)
{
  __shared__ __bf16 zl[MDIM];
  int nd = *dcnt;
  int jb = blockIdx.x;
  int j = jb*64 + threadIdx.x;
  for (int rs = blockIdx.y; rs < nd; rs += RST){
    int t = dlist[rs];
    float prev = prevg[t];
    #pragma unroll
    for (int q=0;q<16;q++){
      int k = threadIdx.x + 64*q;
      __bf16 v = (__bf16)gelu_f(ZP[(size_t)t*MDIM + k] + prev*wlast[k]);
      zl[k] = v;
      if (jb==0) Zb[(size_t)t*MDIM + k] = v;
    }
    __syncthreads();
    const __bf16* w = Wt + (size_t)j*MDIM;
    float acc = 0.f;
    for (int k=0;k<MDIM;k+=8){
      bf16x8 wv = *(const bf16x8*)&w[k];
      bf16x8 iv = *(const bf16x8*)&zl[k];
      #pragma unroll
      for (int u=0;u<8;u++) acc = fmaf((float)wv[u], (float)iv[u], acc);
    }
    Ob[(size_t)t*MDIM + j] = (__bf16)gelu_f(acc + bias[j]);
    __syncthreads();
  }
}

__global__ __launch_bounds__(64) void k_fc2_dirty(
    const __bf16* __restrict__ In, const __bf16* __restrict__ Wt,
    const float* __restrict__ bias, const __bf16* __restrict__ Rz,
    const int* __restrict__ dlist, const int* __restrict__ dcnt,
    float* __restrict__ Of)
{
  int nd = *dcnt;
  int j = blockIdx.x*64 + threadIdx.x;
  for (int rs = blockIdx.y; rs < nd; rs += RST){
    int t = dlist[rs];
    const __bf16* in = In + (size_t)t*MDIM;
    const __bf16* w  = Wt + (size_t)j*MDIM;
    float acc = 0.f;
    for (int k=0;k<MDIM;k+=8){
      bf16x8 wv = *(const bf16x8*)&w[k];
      bf16x8 iv = *(const bf16x8*)&in[k];
      #pragma unroll
      for (int u=0;u<8;u++) acc = fmaf((float)wv[u], (float)iv[u], acc);
    }
    Of[(size_t)t*MDIM + j] = acc + bias[j] + (float)Rz[(size_t)t*MDIM + j];
  }
}

// fused LN + folded-fc1 matvec for dirty rows: zl = raw normalized; Zb = g*zl + b; bias = biasF
__global__ __launch_bounds__(64) void k_lnfc1_dirty(
    const float* __restrict__ Y,
    const float* __restrict__ g, const float* __restrict__ b,
    const __bf16* __restrict__ Wt, const float* __restrict__ biasF,
    const int* __restrict__ dlist, const int* __restrict__ dcnt,
    __bf16* __restrict__ Zb, __bf16* __restrict__ Ob)
{
  __shared__ __bf16 zl[MDIM];
  int nd = *dcnt;
  int jb = blockIdx.x;
  int j = jb*64 + threadIdx.x;
  for (int rs = blockIdx.y; rs < nd; rs += RST){
    int t = dlist[rs];
    float y[16]; float s=0.f, s2=0.f;
    #pragma unroll
    for (int q=0;q<16;q++){
      y[q] = Y[(size_t)t*MDIM + threadIdx.x + 64*q];
      s += y[q]; s2 += y[q]*y[q];
    }
    for (int o=32;o>0;o>>=1){ s += __shfl_down(s,o); s2 += __shfl_down(s2,o); }
    float tot  = __shfl(s, 0);
    float tot2 = __shfl(s2, 0);
    float mean = tot*(1.0f/MDIM);
    float var  = tot2*(1.0f/MDIM) - mean*mean;
    float rs2 = rsqrtf(var + 1e-5f);
    #pragma unroll
    for (int q=0;q<16;q++){
      int k = threadIdx.x + 64*q;
      float raw = (y[q]-mean)*rs2;
      zl[k] = (__bf16)raw;
      if (jb==0) Zb[(size_t)t*MDIM + k] = (__bf16)(g[k]*raw + b[k]);
    }
    __syncthreads();
    const __bf16* w = Wt + (size_t)j*MDIM;
    float acc = 0.f;
    for (int k=0;k<MDIM;k+=8){
      bf16x8 wv = *(const bf16x8*)&w[k];
      bf16x8 iv = *(const bf16x8*)&zl[k];
      #pragma unroll
      for (int u=0;u<8;u++) acc = fmaf((float)wv[u], (float)iv[u], acc);
    }
    Ob[(size_t)t*MDIM + j] = (__bf16)gelu_f(acc + biasF[j]);
    __syncthreads();
  }
}

__global__ __launch_bounds__(64) void k_lnmp_dirty(
    const float* __restrict__ Y,
    const float* __restrict__ g, const float* __restrict__ b,
    const int* __restrict__ dlist, const int* __restrict__ dcnt,
    const float* __restrict__ muw, const float* __restrict__ mub,
    const float* __restrict__ phiw, const float* __restrict__ phib,
    float* __restrict__ muA, float* __restrict__ phiA)
{
  int nd = *dcnt;
  for (int rs = blockIdx.x; rs < nd; rs += RST){
    int t = dlist[rs];
    float y[16]; float s=0.f, s2=0.f;
    #pragma unroll
    for (int q=0;q<16;q++){
      y[q] = Y[(size_t)t*MDIM + threadIdx.x + 64*q];
      s += y[q]; s2 += y[q]*y[q];
    }
    for (int o=32;o>0;o>>=1){ s += __shfl_down(s,o); s2 += __shfl_down(s2,o); }
    float tot  = __shfl(s, 0);
    float tot2 = __shfl(s2, 0);
    float mean = tot*(1.0f/MDIM);
    float var  = tot2*(1.0f/MDIM) - mean*mean;
    float rs2 = rsqrtf(var + 1e-5f);
    float sm=0.f, sp=0.f;
    #pragma unroll
    for (int q=0;q<16;q++){
      int k = threadIdx.x + 64*q;
      float v = g[k]*(y[q]-mean)*rs2 + b[k];
      sm = fmaf(v, muw[k], sm); sp = fmaf(v, phiw[k], sp);
    }
    for (int o=32;o>0;o>>=1){ sm+=__shfl_down(sm,o); sp+=__shfl_down(sp,o); }
    if (threadIdx.x==0){
      muA[t]  = sigmoid_f(sm + mub[0]);
      phiA[t] = softplus_f(sp + phib[0]) + 2.0f;
    }
  }
}

// ---- segmented prefix-product scan (wave shfl, 2 barriers) + dirty detect + output ----
__global__ __launch_bounds__(1024) void k_scan(
    const float* __restrict__ muA, const float* __restrict__ phiA,
    const unsigned char* __restrict__ bmask,
    float* __restrict__ prevg, int* __restrict__ dlist, int* __restrict__ dcnt,
    float* __restrict__ out)
{
  if (*dcnt == 0) return;
  __shared__ float aggP[16];
  __shared__ unsigned aggF[16];
  __shared__ float wprP[16];
  __shared__ unsigned wprF[16];
  __shared__ int cnt;
  int tid = threadIdx.x;
  int wid = tid>>6, lane = tid&63;
  if (tid==0) cnt = 0;
  int i0 = wid*128 + lane*2;
  float mu0 = muA[i0], mu1 = muA[i0+1];
  float p0 = 1.0f - mu0, p1 = 1.0f - mu1;
  unsigned f0 = (i0==0) || (bmask[i0] != 0);
  unsigned f1 = (bmask[i0+1] != 0);
  float    sp_ = f1 ? p1 : p0*p1;
  unsigned sf_ = f0|f1;
  #pragma unroll
  for (int off=1; off<64; off<<=1){
    float    op = __shfl_up(sp_, off);
    unsigned of = __shfl_up(sf_, off);
    if (lane >= off && !sf_){ sp_ = op*sp_; sf_ = of; }
  }
  if (lane==63){ aggP[wid]=sp_; aggF[wid]=sf_; }
  __syncthreads();
  if (wid==0 && lane<16){
    float ap = aggP[lane]; unsigned af = aggF[lane];
    #pragma unroll
    for (int off=1; off<16; off<<=1){
      float    op = __shfl_up(ap, off);
      unsigned of = __shfl_up(af, off);
      if (lane >= off && !af){ ap = op*ap; af = of; }
    }
    wprP[lane]=ap; wprF[lane]=af;
  }
  __syncthreads();
  float    wpP = (wid==0)? 1.0f : wprP[wid-1];
  float    lpP = __shfl_up(sp_, 1);
  unsigned lpF = __shfl_up(sf_, 1);
  float exP;
  if (lane==0){ exP = wpP; }
  else        { exP = lpF ? lpP : wpP*lpP; }
  float i0P = f0 ? p0 : exP*p0;
  float i1P = f1 ? p1 : i0P*p1;
  float prev0 = (i0==0)? -1.0f : (1.0f - exP);
  float prev1 = 1.0f - i0P;
  float rf0 = 1.0f - i0P, rf1 = 1.0f - i1P;
  out[i0]   = rf0;  out[i0+1]   = rf1;
  out[TSEQ+i0] = mu0; out[TSEQ+i0+1] = mu1;
  out[2*TSEQ+i0] = phiA[i0]; out[2*TSEQ+i0+1] = phiA[i0+1];
  float old0 = prevg[i0], old1 = prevg[i0+1];
  prevg[i0] = prev0; prevg[i0+1] = prev1;
  if (fabsf(prev0 - old0) > 1e-3f){ int pos = atomicAdd(&cnt,1); dlist[pos] = i0; }
  if (fabsf(prev1 - old1) > 1e-3f){ int pos = atomicAdd(&cnt,1); dlist[pos] = i0+1; }
  __syncthreads();
  if (tid==0) *dcnt = cnt;
}

extern "C" void kernel_launch(void* const* d_in, const int* in_sizes, int n_in,
                              void* d_out, int out_size, void* d_ws, size_t ws_size,
                              hipStream_t stream) {
  const float* mol       = (const float*)d_in[0];
  const float* ratios    = (const float*)d_in[1];
  const float* desc      = (const float*)d_in[2];
  const float* svvec     = (const float*)d_in[3];
  const unsigned char* bmask = (const unsigned char*)d_in[4];
  const float* sp_proj_w = (const float*)d_in[5];
  const float* sp_proj_b = (const float*)d_in[6];
  const float* sp_fc1_w  = (const float*)d_in[7];
  const float* sp_fc1_b  = (const float*)d_in[8];
  const float* sp_fc2_w  = (const float*)d_in[9];
  const float* sp_fc2_b  = (const float*)d_in[10];
  const float* sp_ln_g   = (const float*)d_in[11];
  const float* sp_ln_b   = (const float*)d_in[12];
  const float* desc_w    = (const float*)d_in[13];
  const float* desc_b    = (const float*)d_in[14];
  const float* bh_proj_w = (const float*)d_in[15];
  const float* bh_proj_b = (const float*)d_in[16];
  const float* bh_fc1_w  = (const float*)d_in[17];
  const float* bh_fc1_b  = (const float*)d_in[18];
  const float* bh_fc2_w  = (const float*)d_in[19];
  const float* bh_fc2_b  = (const float*)d_in[20];
  const float* bh_ln_g   = (const float*)d_in[21];
  const float* bh_ln_b   = (const float*)d_in[22];
  const float* mu_w      = (const float*)d_in[23];
  const float* mu_b      = (const float*)d_in[24];
  const float* phi_w     = (const float*)d_in[25];
  const float* phi_b     = (const float*)d_in[26];
  float* out = (float*)d_out;

  char* p = (char*)d_ws;
  auto alloc = [&](size_t bytes)->char*{ char* r = p; p += (bytes + 255) & ~(size_t)255; return r; };
  const size_t MM = (size_t)MDIM*MDIM;
  __bf16* Xb   = (__bf16*)alloc((size_t)TSEQ*XLDB*2);
  __bf16* Zb   = (__bf16*)alloc((size_t)TSEQ*MDIM*2);
  __bf16* Yb0  = (__bf16*)alloc((size_t)TSEQ*MDIM*2);
  __bf16* Yb1  = (__bf16*)alloc((size_t)TSEQ*MDIM*2);
  float*  Y    = (float*)alloc((size_t)TSEQ*MDIM*4);
  float*  ZP   = (float*)alloc((size_t)TSEQ*MDIM*4);
  __bf16* Hb16 = (__bf16*)alloc((size_t)TSEQ*MDIM*2);
  __bf16* WALL = (__bf16*)alloc(12*MM*2);
  __bf16* WpT  = (__bf16*)alloc((size_t)MDIM*XLDB*2);
  float*  PART = (float*)alloc((size_t)16*NRED*4);
  float*  P    = (float*)alloc((size_t)NSOL*MDIM*4);
  float*  mp   = (float*)alloc(MDIM*4);
  float*  prevg= (float*)alloc(TSEQ*4);
  float*  muA  = (float*)alloc(TSEQ*4);
  float*  phiA = (float*)alloc(TSEQ*4);
  int*    dlist= (int*)alloc(TSEQ*4);
  int*    dcnt = (int*)alloc(256);
  float*  pAS  = (float*)alloc((size_t)16*2048*4);
  float*  pAQ  = (float*)alloc((size_t)16*2048*4);
  float*  pBS  = (float*)alloc((size_t)16*2048*4);
  float*  pBQ  = (float*)alloc((size_t)16*2048*4);
  float*  S1buf= (float*)alloc(4*MDIM*4);
  float*  biasF= (float*)alloc(4*MDIM*4);
  __bf16* W1T = WALL, *W2T = WALL + 3*MM, *U1T = WALL + 6*MM, *U2T = WALL + 9*MM;

  k_cvtT13<<<dim3(32,34,13),256,0,stream>>>(sp_fc1_w, sp_fc2_w, bh_fc1_w, bh_fc2_w,
      bh_proj_w + MM, WALL, WpT, sp_ln_g, bh_ln_g);
  k_pm<<<dim3(4,10,16),256,0,stream>>>(svvec, sp_proj_w, mol, bh_proj_w, PART,
      sp_fc1_w, bh_fc1_w, sp_ln_g, sp_ln_b, bh_ln_g, bh_ln_b);
  k_red<<<dim3(NRED/256),256,0,stream>>>(PART, bh_proj_b, P, mp, prevg, dlist, dcnt,
      sp_fc1_b, bh_fc1_b, S1buf, biasF);
  k_sp0d<<<dim3(5,TSEQ),256,0,stream>>>(ratios, P, sp_proj_b, desc, desc_w, desc_b, Xb);

  const float* wlast = bh_proj_w + (size_t)2112*MDIM;
  dim3 gg(16,16);
  // ---- sp chain ----
  k_mfma_gemm<128,true,false,false,false,true,false,false,false><<<gg,512,0,stream>>>(
      Xb, XLDB, 1024, W1T, sp_fc1_b, nullptr, 0, nullptr, 0, Hb16, MDIM,
      nullptr, nullptr, nullptr, nullptr, nullptr, nullptr, nullptr, nullptr, nullptr, nullptr, nullptr);
  k_mfma_gemm<128,false,true,false,false,true,false,false,true><<<gg,512,0,stream>>>(
      Hb16, MDIM, 1024, W2T, sp_fc2_b, Xb, XLDB, nullptr, 0, Yb0, MDIM,
      nullptr, nullptr, nullptr, nullptr, nullptr, pAS, pAQ, nullptr, nullptr, nullptr, nullptr);
  k_mfma_gemm<128,false,false,false,false,true,false,true,false><<<gg,512,0,stream>>>(
      Yb0, MDIM, 1024, W1T + 1*MM, nullptr, nullptr, 0, nullptr, 0, Hb16, MDIM,
      nullptr, nullptr, nullptr, pAS, pAQ, nullptr, nullptr, S1buf, biasF, nullptr, nullptr);
  k_mfma_gemm<128,false,false,true,false,true,false,false,true><<<gg,512,0,stream>>>(
      Hb16, MDIM, 1024, W2T + 1*MM, sp_fc2_b + 1024, Yb0, MDIM, nullptr, 0, Yb1, MDIM,
      nullptr, nullptr, nullptr, pAS, pAQ, pBS, pBQ, nullptr, nullptr, sp_ln_g, sp_ln_b);
  k_mfma_gemm<128,false,false,false,false,true,false,true,false><<<gg,512,0,stream>>>(
      Yb1, MDIM, 1024, W1T + 2*MM, nullptr, nullptr, 0, nullptr, 0, Hb16, MDIM,
      nullptr, nullptr, nullptr, pBS, pBQ, nullptr, nullptr, S1buf + 1024, biasF + 1024, nullptr, nullptr);
  k_mfma_gemm<128,false,false,true,true,false,false,false,false><<<gg,512,0,stream>>>(
      Hb16, MDIM, 1024, W2T + 2*MM, sp_fc2_b + 2048, Yb1, MDIM, Y, MDIM, nullptr, 0,
      nullptr, nullptr, nullptr, pBS, pBQ, nullptr, nullptr, nullptr, nullptr, sp_ln_g + 1024, sp_ln_b + 1024);
  k_ln<false><<<dim3(TSEQ),256,0,stream>>>(Y, MDIM, Xb, XLDB,
      sp_ln_g + 2048, sp_ln_b + 2048, nullptr, nullptr, nullptr, nullptr, nullptr, nullptr);
  // ---- z_pre GEMM (K=1088) with fused speculative z0 -> Zb ----
  k_mfma_gemm<64,false,false,false,true,false,true,false,false><<<gg,512,0,stream>>>(
      Xb, XLDB, XLDB, WpT, mp, nullptr, 0, ZP, MDIM, nullptr, 0,
      wlast, prevg, Zb, nullptr, nullptr, nullptr, nullptr, nullptr, nullptr, nullptr, nullptr);
  // ---- head chain (iteration 1, speculative prev) ----
  k_mfma_gemm<128,true,false,false,false,true,false,false,false><<<gg,512,0,stream>>>(
      Zb, MDIM, 1024, U1T, bh_fc1_b, nullptr, 0, nullptr, 0, Hb16, MDIM,
      nullptr, nullptr, nullptr, nullptr, nullptr, nullptr, nullptr, nullptr, nullptr, nullptr, nullptr);
  k_mfma_gemm<128,false,true,false,false,true,false,false,true><<<gg,512,0,stream>>>(
      Hb16, MDIM, 1024, U2T, bh_fc2_b, Zb, MDIM, nullptr, 0, Yb0, MDIM,
      nullptr, nullptr, nullptr, nullptr, nullptr, pAS, pAQ, nullptr, nullptr, nullptr, nullptr);
  k_mfma_gemm<128,false,false,false,false,true,false,true,false><<<gg,512,0,stream>>>(
      Yb0, MDIM, 1024, U1T + 1*MM, nullptr, nullptr, 0, nullptr, 0, Hb16, MDIM,
      nullptr, nullptr, nullptr, pAS, pAQ, nullptr, nullptr, S1buf + 2048, biasF + 2048, nullptr, nullptr);
  k_mfma_gemm<128,false,false,true,false,true,false,false,true><<<gg,512,0,stream>>>(
      Hb16, MDIM, 1024, U2T + 1*MM, bh_fc2_b + 1024, Yb0, MDIM, nullptr, 0, Yb1, MDIM,
      nullptr, nullptr, nullptr, pAS, pAQ, pBS, pBQ, nullptr, nullptr, bh_ln_g, bh_ln_b);
  k_mfma_gemm<128,false,false,false,false,true,false,true,false><<<gg,512,0,stream>>>(
      Yb1, MDIM, 1024, U1T + 2*MM, nullptr, nullptr, 0, nullptr, 0, Hb16, MDIM,
      nullptr, nullptr, nullptr, pBS, pBQ, nullptr, nullptr, S1buf + 3072, biasF + 3072, nullptr, nullptr);
  k_mfma_gemm<128,false,false,true,true,false,false,false,false><<<gg,512,0,stream>>>(
      Hb16, MDIM, 1024, U2T + 2*MM, bh_fc2_b + 2048, Yb1, MDIM, Y, MDIM, nullptr, 0,
      nullptr, nullptr, nullptr, pBS, pBQ, nullptr, nullptr, nullptr, nullptr, bh_ln_g + 1024, bh_ln_b + 1024);
  k_ln<true><<<dim3(TSEQ),256,0,stream>>>(Y, MDIM, Zb, MDIM,
      bh_ln_g + 2048, bh_ln_b + 2048, mu_w, mu_b, phi_w, phi_b, muA, phiA);
  k_scan<<<dim3(1),1024,0,stream>>>(muA, phiA, bmask, prevg, dlist, dcnt, out);

  // ---- refinement: one staged dirty-row pass + final scan ----
  for (int it=1; it<KITER; it++){
    k_fc1z_dirty<<<dim3(16,RST),64,0,stream>>>(ZP, wlast, prevg,
        U1T, bh_fc1_b, dlist, dcnt, Zb, Hb16);
    k_fc2_dirty<<<dim3(16,RST),64,0,stream>>>(
        Hb16, U2T, bh_fc2_b, Zb, dlist, dcnt, Y);
    for (int i=1;i<NBLK;i++){
      k_lnfc1_dirty<<<dim3(16,RST),64,0,stream>>>(Y,
          bh_ln_g + (i-1)*MDIM, bh_ln_b + (i-1)*MDIM,
          U1T + (size_t)i*MM, biasF + (i+1)*MDIM, dlist, dcnt, Zb, Hb16);
      k_fc2_dirty<<<dim3(16,RST),64,0,stream>>>(
          Hb16, U2T + (size_t)i*MM, bh_fc2_b + i*MDIM, Zb, dlist, dcnt, Y);
    }
    k_lnmp_dirty<<<dim3(RST),64,0,stream>>>(Y,
        bh_ln_g + (NBLK-1)*MDIM, bh_ln_b + (NBLK-1)*MDIM,
        dlist, dcnt, mu_w, mu_b, phi_w, phi_b, muA, phiA);
    k_scan<<<dim3(1),1024,0,stream>>>(muA, phiA, bmask, prevg, dlist, dcnt, out);
  }
  (void)in_sizes; (void)n_in; (void)out_size; (void)ws_size;
}